// Round 6
// baseline (452.282 us; speedup 1.0000x reference)
//
#include <hip/hip_runtime.h>
#include <stdint.h>

#define D 128
#define NCLS 64
#define BSH 7       // 128 nodes per bucket
#define NBMAX 1024  // max buckets (N <= 131072)
#define CCHUNK 4096 // edges per k_bscatter block
#define ATS 132     // LDS A-tile row stride (ushorts): 8B-aligned rows, breaks bank alignment

typedef __bf16 bf16x8 __attribute__((ext_vector_type(8)));
typedef float f32x4 __attribute__((ext_vector_type(4)));

union B8 { uint4 u; bf16x8 v; };

// ---- f32 -> bf16 bulk convert: features + all weights, one launch --------

__global__ __launch_bounds__(256) void k_prep(const float* __restrict__ feat,
                                              const float* __restrict__ W1,
                                              const float* __restrict__ W2,
                                              const float* __restrict__ Wl,
                                              ushort* __restrict__ featb,
                                              ushort* __restrict__ W1b,
                                              ushort* __restrict__ W2b,
                                              ushort* __restrict__ Wlb, int n8feat) {
  const int n1 = D * D / 8;        // 2048 groups per 128x128 weight
  const int nl = 2 * D * NCLS / 8; // 4096 groups for Wl
  int t = blockIdx.x * 256 + threadIdx.x;
  const float* xp; ushort* yp; int idx;
  if (t < n8feat) { xp = feat; yp = featb; idx = t; }
  else {
    t -= n8feat;
    if (t < n1) { xp = W1; yp = W1b; idx = t; }
    else if (t < 2 * n1) { xp = W2; yp = W2b; idx = t - n1; }
    else if (t < 2 * n1 + nl) { xp = Wl; yp = Wlb; idx = t - 2 * n1; }
    else return;
  }
  const float4 a = reinterpret_cast<const float4*>(xp)[idx * 2 + 0];
  const float4 b = reinterpret_cast<const float4*>(xp)[idx * 2 + 1];
  union { __bf16 h[8]; uint4 u; } p;
  p.h[0] = (__bf16)a.x; p.h[1] = (__bf16)a.y; p.h[2] = (__bf16)a.z; p.h[3] = (__bf16)a.w;
  p.h[4] = (__bf16)b.x; p.h[5] = (__bf16)b.y; p.h[6] = (__bf16)b.z; p.h[7] = (__bf16)b.w;
  reinterpret_cast<uint4*>(yp)[idx] = p.u;
}

// ---- bucketed CSR build --------------------------------------------------

__global__ __launch_bounds__(256) void k_bhist(const int* __restrict__ dst,
                                               int* __restrict__ bcnt, int E, int NB) {
  __shared__ int h[NBMAX];
  for (int i = threadIdx.x; i < NB; i += 256) h[i] = 0;
  __syncthreads();
  for (int e = blockIdx.x * 256 + threadIdx.x; e < E; e += gridDim.x * 256)
    atomicAdd(&h[dst[e] >> BSH], 1);
  __syncthreads();
  for (int i = threadIdx.x; i < NB; i += 256) {
    int c = h[i];
    if (c) atomicAdd(&bcnt[i], c);
  }
}

__global__ __launch_bounds__(1024) void k_bscan(const int* __restrict__ bcnt,
                                                int* __restrict__ bbase,
                                                int* __restrict__ bcur, int NB, int E) {
  __shared__ int sm[NBMAX];
  const int tid = threadIdx.x;
  int v = (tid < NB) ? bcnt[tid] : 0;
  sm[tid] = v;
  __syncthreads();
  for (int off = 1; off < NBMAX; off <<= 1) {
    int t = (tid >= off) ? sm[tid - off] : 0;
    __syncthreads();
    sm[tid] += t;
    __syncthreads();
  }
  if (tid < NB) {
    bbase[tid] = sm[tid] - v;
    bcur[tid] = sm[tid] - v;
  }
  if (tid == 0) bbase[NB] = E;
}

__global__ __launch_bounds__(256) void k_bscatter(const int* __restrict__ src,
                                                  const int* __restrict__ dst,
                                                  int* __restrict__ bcur,
                                                  int* __restrict__ ebuck, int E, int NB) {
  __shared__ int h[NBMAX];
  __shared__ int base[NBMAX];
  const int beg = blockIdx.x * CCHUNK;
  const int end = min(beg + CCHUNK, E);
  for (int i = threadIdx.x; i < NB; i += 256) h[i] = 0;
  __syncthreads();
  for (int e = beg + threadIdx.x; e < end; e += 256)
    atomicAdd(&h[dst[e] >> BSH], 1);
  __syncthreads();
  for (int i = threadIdx.x; i < NB; i += 256) {
    int c = h[i];
    base[i] = c ? atomicAdd(&bcur[i], c) : 0;
    h[i] = 0;  // becomes local rank cursor
  }
  __syncthreads();
  for (int e = beg + threadIdx.x; e < end; e += 256) {
    const int d = dst[e];
    const int b = d >> BSH;
    const int r = atomicAdd(&h[b], 1);
    ebuck[base[b] + r] = (src[e] << BSH) | (d & 127);
  }
}

__global__ __launch_bounds__(256) void k_bbuild(const int* __restrict__ ebuck,
                                                const int* __restrict__ bbase,
                                                int* __restrict__ row_ptr,
                                                int* __restrict__ esrc,
                                                float* __restrict__ inv, int N, int E) {
  __shared__ int cnt[128], s[128], cur[128];
  const int b = blockIdx.x;
  const int n0 = b << BSH;
  const int nn = min(128, N - n0);
  const int beg = bbase[b], end = bbase[b + 1];
  const int tid = threadIdx.x;
  if (tid < 128) cnt[tid] = 0;
  __syncthreads();
  for (int e = beg + tid; e < end; e += 256)
    atomicAdd(&cnt[ebuck[e] & 127], 1);
  __syncthreads();
  if (tid < 128) s[tid] = cnt[tid];
  __syncthreads();
  for (int off = 1; off < 128; off <<= 1) {
    int t = (tid < 128 && tid >= off) ? s[tid - off] : 0;
    __syncthreads();
    if (tid < 128) s[tid] += t;
    __syncthreads();
  }
  if (tid < 128) {
    const int ex = s[tid] - cnt[tid];
    cur[tid] = ex;
    if (tid < nn) {
      row_ptr[n0 + tid] = beg + ex;
      inv[n0 + tid] = 1.0f / fmaxf((float)cnt[tid], 1.0f);
    }
  }
  if (b == 0 && tid == 0) row_ptr[N] = E;
  __syncthreads();
  for (int e = beg + tid; e < end; e += 256) {
    const int p = ebuck[e];
    const int r = atomicAdd(&cur[p & 127], 1);
    esrc[beg + r] = p >> BSH;
  }
}

// ---- fused layer: gather-mean (CSR) -> LDS tile -> MFMA -> relu -> store --
// Block = 16-row M-tile. Wave w gathers nodes mt*16+w*4+{0..3} (unroll-4 edge
// loop, 4 outstanding 256B row loads), packs bf16 rows into LDS, then computes
// cols [w*32, w*32+32) with 8 MFMAs. agg never touches global memory.

__global__ __launch_bounds__(256) void k_layer(const ushort* __restrict__ h,
                                               const int* __restrict__ row_ptr,
                                               const int* __restrict__ esrc,
                                               const float* __restrict__ inv,
                                               const ushort* __restrict__ Wb,
                                               const float* __restrict__ bias,
                                               ushort* __restrict__ Hout, int N) {
  __shared__ ushort At[16][ATS];
  const int wave = threadIdx.x >> 6;
  const int lane = threadIdx.x & 63;
  const int l15 = lane & 15;
  const int quad = lane >> 4;

  B8 bfrag[2][4];
  float bv[2];
#pragma unroll
  for (int t = 0; t < 2; ++t) {
    const int n = wave * 32 + t * 16 + l15;
    bv[t] = bias[n];
#pragma unroll
    for (int ks = 0; ks < 4; ++ks)
      bfrag[t][ks].u = *reinterpret_cast<const uint4*>(Wb + n * D + ks * 32 + quad * 8);
  }

  const ushort* hp = h + lane * 2;
  const int mtiles = N >> 4;
  for (int mt = blockIdx.x; mt < mtiles; mt += gridDim.x) {
    // ---- gather phase: 4 nodes per wave ----
#pragma unroll
    for (int i = 0; i < 4; ++i) {
      const int node = mt * 16 + wave * 4 + i;
      const int beg = row_ptr[node];
      const int end = row_ptr[node + 1];
      float ax = 0.f, ay = 0.f, bx = 0.f, by = 0.f;
      int e = beg;
      for (; e + 3 < end; e += 4) {
        const int s0 = esrc[e + 0];
        const int s1 = esrc[e + 1];
        const int s2 = esrc[e + 2];
        const int s3 = esrc[e + 3];
        const unsigned int u0 = *reinterpret_cast<const unsigned int*>(hp + (size_t)s0 * D);
        const unsigned int u1 = *reinterpret_cast<const unsigned int*>(hp + (size_t)s1 * D);
        const unsigned int u2 = *reinterpret_cast<const unsigned int*>(hp + (size_t)s2 * D);
        const unsigned int u3 = *reinterpret_cast<const unsigned int*>(hp + (size_t)s3 * D);
        ax += __uint_as_float(u0 << 16) + __uint_as_float(u1 << 16);
        ay += __uint_as_float(u0 & 0xffff0000u) + __uint_as_float(u1 & 0xffff0000u);
        bx += __uint_as_float(u2 << 16) + __uint_as_float(u3 << 16);
        by += __uint_as_float(u2 & 0xffff0000u) + __uint_as_float(u3 & 0xffff0000u);
      }
      if (e + 1 < end) {
        const int s0 = esrc[e + 0];
        const int s1 = esrc[e + 1];
        const unsigned int u0 = *reinterpret_cast<const unsigned int*>(hp + (size_t)s0 * D);
        const unsigned int u1 = *reinterpret_cast<const unsigned int*>(hp + (size_t)s1 * D);
        ax += __uint_as_float(u0 << 16) + __uint_as_float(u1 << 16);
        ay += __uint_as_float(u0 & 0xffff0000u) + __uint_as_float(u1 & 0xffff0000u);
        e += 2;
      }
      if (e < end) {
        const unsigned int u0 = *reinterpret_cast<const unsigned int*>(hp + (size_t)esrc[e] * D);
        ax += __uint_as_float(u0 << 16);
        ay += __uint_as_float(u0 & 0xffff0000u);
      }
      ax += bx;
      ay += by;
      const float iv = inv[node];
      union { __bf16 b[2]; unsigned int u; } p;
      p.b[0] = (__bf16)(ax * iv);
      p.b[1] = (__bf16)(ay * iv);
      *reinterpret_cast<unsigned int*>(&At[wave * 4 + i][lane * 2]) = p.u;
    }
    __syncthreads();
    // ---- MFMA phase ----
    B8 afr[4];
#pragma unroll
    for (int ks = 0; ks < 4; ++ks) {
      const ushort* ap = &At[l15][ks * 32 + quad * 8];
      const uint2 lo = *reinterpret_cast<const uint2*>(ap);
      const uint2 hi = *reinterpret_cast<const uint2*>(ap + 4);
      afr[ks].u = make_uint4(lo.x, lo.y, hi.x, hi.y);
    }
#pragma unroll
    for (int t = 0; t < 2; ++t) {
      f32x4 acc = {0.f, 0.f, 0.f, 0.f};
      acc = __builtin_amdgcn_mfma_f32_16x16x32_bf16(afr[0].v, bfrag[t][0].v, acc, 0, 0, 0);
      acc = __builtin_amdgcn_mfma_f32_16x16x32_bf16(afr[1].v, bfrag[t][1].v, acc, 0, 0, 0);
      acc = __builtin_amdgcn_mfma_f32_16x16x32_bf16(afr[2].v, bfrag[t][2].v, acc, 0, 0, 0);
      acc = __builtin_amdgcn_mfma_f32_16x16x32_bf16(afr[3].v, bfrag[t][3].v, acc, 0, 0, 0);
      const int col = wave * 32 + t * 16 + l15;
#pragma unroll
      for (int r = 0; r < 4; ++r) {
        const int row = mt * 16 + quad * 4 + r;
        const float v = fmaxf(acc[r] + bv[t], 0.f);
        union { __bf16 b; ushort s; } c;
        c.b = (__bf16)v;
        Hout[(size_t)row * D + col] = c.s;
      }
    }
    __syncthreads();
  }
}

// ---- logits + log_softmax fused (Wl pre-converted bf16 [n][k]) -----------

__global__ __launch_bounds__(256) void k_logits_sm(const ushort* __restrict__ H1,
                                                   const ushort* __restrict__ H2,
                                                   const ushort* __restrict__ Wlb,
                                                   const float* __restrict__ bl,
                                                   float* __restrict__ out, int N) {
  __shared__ float L[16][NCLS + 4];
  const int wave = threadIdx.x >> 6;
  const int lane = threadIdx.x & 63;
  const int l15 = lane & 15;
  const int quad = lane >> 4;

  B8 bfrag[8];
  const int n = wave * 16 + l15;
  const float bb = bl[n];
#pragma unroll
  for (int ks = 0; ks < 8; ++ks)
    bfrag[ks].u = *reinterpret_cast<const uint4*>(Wlb + n * (2 * D) + ks * 32 + quad * 8);

  const int mtiles = N >> 4;
  for (int mt = blockIdx.x; mt < mtiles; mt += gridDim.x) {
    const size_t rb = (size_t)(mt * 16 + l15) * D + quad * 8;
    f32x4 acc = {0.f, 0.f, 0.f, 0.f};
    B8 a;
#pragma unroll
    for (int ks = 0; ks < 4; ++ks) {
      a.u = *reinterpret_cast<const uint4*>(H1 + rb + ks * 32);
      acc = __builtin_amdgcn_mfma_f32_16x16x32_bf16(a.v, bfrag[ks].v, acc, 0, 0, 0);
    }
#pragma unroll
    for (int ks = 0; ks < 4; ++ks) {
      a.u = *reinterpret_cast<const uint4*>(H2 + rb + ks * 32);
      acc = __builtin_amdgcn_mfma_f32_16x16x32_bf16(a.v, bfrag[4 + ks].v, acc, 0, 0, 0);
    }
#pragma unroll
    for (int r = 0; r < 4; ++r)
      L[quad * 4 + r][wave * 16 + l15] = acc[r] + bb;
    __syncthreads();
#pragma unroll
    for (int r = 0; r < 4; ++r) {
      const int row = wave * 4 + r;
      float v = L[row][lane];
      float m = v;
#pragma unroll
      for (int off = 32; off > 0; off >>= 1) m = fmaxf(m, __shfl_xor(m, off));
      float e = __expf(v - m);
#pragma unroll
      for (int off = 32; off > 0; off >>= 1) e += __shfl_xor(e, off);
      out[(size_t)(mt * 16 + row) * NCLS + lane] = v - m - __logf(e);
    }
    __syncthreads();
  }
}

// ---- driver --------------------------------------------------------------

extern "C" void kernel_launch(void* const* d_in, const int* in_sizes, int n_in,
                              void* d_out, int out_size, void* d_ws, size_t ws_size,
                              hipStream_t stream) {
  const float* feat = (const float*)d_in[0];
  const int* src = (const int*)d_in[1];
  const int* dst = (const int*)d_in[2];
  const float* W1 = (const float*)d_in[3];
  const float* b1 = (const float*)d_in[4];
  const float* W2 = (const float*)d_in[5];
  const float* b2 = (const float*)d_in[6];
  const float* Wl = (const float*)d_in[7];
  const float* bl = (const float*)d_in[8];
  float* out = (float*)d_out;

  const int N = in_sizes[0] / D;  // 100000
  const int E = in_sizes[1];      // 1600000
  const int NB = (N + 127) >> BSH;  // 782

  // workspace layout
  float* ws = (float*)d_ws;
  float* inv = ws;                          // N
  ushort* featb = (ushort*)(inv + N);       // N*D
  ushort* scratch = featb + (size_t)N * D;  // N*D (ebuck lives here)
  ushort* h1b = scratch + (size_t)N * D;    // N*D
  ushort* h2b = h1b + (size_t)N * D;        // N*D
  int* row_ptr = (int*)(h2b + (size_t)N * D);  // N+1
  int* esrc = row_ptr + N + 1;              // E
  int* bcnt = esrc + E;                     // NBMAX
  int* bbase = bcnt + NBMAX;                // NBMAX+1
  int* bcur = bbase + NBMAX + 1;            // NBMAX
  ushort* W1b = (ushort*)(bcur + NBMAX);    // D*D
  ushort* W2b = W1b + D * D;                // D*D
  ushort* Wlb = W2b + D * D;                // 2*D*NCLS
  int* ebuck = (int*)scratch;               // E ints, dead after k_bbuild

  hipMemsetAsync(bcnt, 0, NBMAX * sizeof(int), stream);

  // bf16 copies: features + weights (one launch)
  const int n8 = N * D / 8;
  const int prepTot = n8 + 2 * (D * D / 8) + (2 * D * NCLS / 8);
  k_prep<<<(prepTot + 255) / 256, 256, 0, stream>>>(feat, W1, W2, Wl,
                                                    featb, W1b, W2b, Wlb, n8);

  // bucketed CSR build
  k_bhist<<<256, 256, 0, stream>>>(dst, bcnt, E, NB);
  k_bscan<<<1, 1024, 0, stream>>>(bcnt, bbase, bcur, NB, E);
  k_bscatter<<<(E + CCHUNK - 1) / CCHUNK, 256, 0, stream>>>(src, dst, bcur, ebuck, E, NB);
  k_bbuild<<<NB, 256, 0, stream>>>(ebuck, bbase, row_ptr, esrc, inv, N, E);

  // layer 1: h1 = relu(mean(feat[neigh]) @ W1^T + b1), fused
  k_layer<<<2048, 256, 0, stream>>>(featb, row_ptr, esrc, inv, W1b, b1, h1b, N);

  // layer 2
  k_layer<<<2048, 256, 0, stream>>>(h1b, row_ptr, esrc, inv, W2b, b2, h2b, N);

  // logits + log_softmax
  k_logits_sm<<<1024, 256, 0, stream>>>(h1b, h2b, Wlb, bl, out, N);
}

// Round 7
// 372.667 us; speedup vs baseline: 1.2136x; 1.2136x over previous
//
#include <hip/hip_runtime.h>
#include <stdint.h>

#define D 128
#define NCLS 64
#define BSH 7       // 128 nodes per bucket
#define NBMAX 1024  // max buckets (N <= 131072)
#define CCHUNK 4096 // edges per k_bscatter block

typedef __bf16 bf16x8 __attribute__((ext_vector_type(8)));
typedef float f32x4 __attribute__((ext_vector_type(4)));

union B8 { uint4 u; bf16x8 v; };

// ---- f32 -> bf16 bulk convert: features + all weights, one launch --------

__global__ __launch_bounds__(256) void k_prep(const float* __restrict__ feat,
                                              const float* __restrict__ W1,
                                              const float* __restrict__ W2,
                                              const float* __restrict__ Wl,
                                              ushort* __restrict__ featb,
                                              ushort* __restrict__ W1b,
                                              ushort* __restrict__ W2b,
                                              ushort* __restrict__ Wlb, int n8feat) {
  const int n1 = D * D / 8;
  const int nl = 2 * D * NCLS / 8;
  int t = blockIdx.x * 256 + threadIdx.x;
  const float* xp; ushort* yp; int idx;
  if (t < n8feat) { xp = feat; yp = featb; idx = t; }
  else {
    t -= n8feat;
    if (t < n1) { xp = W1; yp = W1b; idx = t; }
    else if (t < 2 * n1) { xp = W2; yp = W2b; idx = t - n1; }
    else if (t < 2 * n1 + nl) { xp = Wl; yp = Wlb; idx = t - 2 * n1; }
    else return;
  }
  const float4 a = reinterpret_cast<const float4*>(xp)[idx * 2 + 0];
  const float4 b = reinterpret_cast<const float4*>(xp)[idx * 2 + 1];
  union { __bf16 h[8]; uint4 u; } p;
  p.h[0] = (__bf16)a.x; p.h[1] = (__bf16)a.y; p.h[2] = (__bf16)a.z; p.h[3] = (__bf16)a.w;
  p.h[4] = (__bf16)b.x; p.h[5] = (__bf16)b.y; p.h[6] = (__bf16)b.z; p.h[7] = (__bf16)b.w;
  reinterpret_cast<uint4*>(yp)[idx] = p.u;
}

// ---- bucketed CSR build --------------------------------------------------

__global__ __launch_bounds__(256) void k_bhist(const int* __restrict__ dst,
                                               int* __restrict__ bcnt, int E, int NB) {
  __shared__ int h[NBMAX];
  for (int i = threadIdx.x; i < NB; i += 256) h[i] = 0;
  __syncthreads();
  for (int e = blockIdx.x * 256 + threadIdx.x; e < E; e += gridDim.x * 256)
    atomicAdd(&h[dst[e] >> BSH], 1);
  __syncthreads();
  for (int i = threadIdx.x; i < NB; i += 256) {
    int c = h[i];
    if (c) atomicAdd(&bcnt[i], c);
  }
}

__global__ __launch_bounds__(1024) void k_bscan(const int* __restrict__ bcnt,
                                                int* __restrict__ bbase,
                                                int* __restrict__ bcur, int NB, int E) {
  __shared__ int sm[NBMAX];
  const int tid = threadIdx.x;
  int v = (tid < NB) ? bcnt[tid] : 0;
  sm[tid] = v;
  __syncthreads();
  for (int off = 1; off < NBMAX; off <<= 1) {
    int t = (tid >= off) ? sm[tid - off] : 0;
    __syncthreads();
    sm[tid] += t;
    __syncthreads();
  }
  if (tid < NB) {
    bbase[tid] = sm[tid] - v;
    bcur[tid] = sm[tid] - v;
  }
  if (tid == 0) bbase[NB] = E;
}

__global__ __launch_bounds__(256) void k_bscatter(const int* __restrict__ src,
                                                  const int* __restrict__ dst,
                                                  int* __restrict__ bcur,
                                                  int* __restrict__ ebuck, int E, int NB) {
  __shared__ int h[NBMAX];
  __shared__ int base[NBMAX];
  const int beg = blockIdx.x * CCHUNK;
  const int end = min(beg + CCHUNK, E);
  for (int i = threadIdx.x; i < NB; i += 256) h[i] = 0;
  __syncthreads();
  for (int e = beg + threadIdx.x; e < end; e += 256)
    atomicAdd(&h[dst[e] >> BSH], 1);
  __syncthreads();
  for (int i = threadIdx.x; i < NB; i += 256) {
    int c = h[i];
    base[i] = c ? atomicAdd(&bcur[i], c) : 0;
    h[i] = 0;  // becomes local rank cursor
  }
  __syncthreads();
  for (int e = beg + threadIdx.x; e < end; e += 256) {
    const int d = dst[e];
    const int b = d >> BSH;
    const int r = atomicAdd(&h[b], 1);
    ebuck[base[b] + r] = (src[e] << BSH) | (d & 127);
  }
}

__global__ __launch_bounds__(256) void k_bbuild(const int* __restrict__ ebuck,
                                                const int* __restrict__ bbase,
                                                int* __restrict__ row_ptr,
                                                int* __restrict__ esrc,
                                                float* __restrict__ inv, int N, int E) {
  __shared__ int cnt[128], s[128], cur[128];
  const int b = blockIdx.x;
  const int n0 = b << BSH;
  const int nn = min(128, N - n0);
  const int beg = bbase[b], end = bbase[b + 1];
  const int tid = threadIdx.x;
  if (tid < 128) cnt[tid] = 0;
  __syncthreads();
  for (int e = beg + tid; e < end; e += 256)
    atomicAdd(&cnt[ebuck[e] & 127], 1);
  __syncthreads();
  if (tid < 128) s[tid] = cnt[tid];
  __syncthreads();
  for (int off = 1; off < 128; off <<= 1) {
    int t = (tid < 128 && tid >= off) ? s[tid - off] : 0;
    __syncthreads();
    if (tid < 128) s[tid] += t;
    __syncthreads();
  }
  if (tid < 128) {
    const int ex = s[tid] - cnt[tid];
    cur[tid] = ex;
    if (tid < nn) {
      row_ptr[n0 + tid] = beg + ex;
      inv[n0 + tid] = 1.0f / fmaxf((float)cnt[tid], 1.0f);
    }
  }
  if (b == 0 && tid == 0) row_ptr[N] = E;
  __syncthreads();
  for (int e = beg + tid; e < end; e += 256) {
    const int p = ebuck[e];
    const int r = atomicAdd(&cur[p & 127], 1);
    esrc[beg + r] = p >> BSH;
  }
}

// ---- mean aggregation via CSR gather: one wave per node, bf16 ------------
// unroll-8: 8 independent 256 B row-loads in flight per wave

__global__ __launch_bounds__(256) void k_gather_mean(const ushort* __restrict__ h,
                                                     const int* __restrict__ row_ptr,
                                                     const int* __restrict__ esrc,
                                                     const float* __restrict__ inv,
                                                     ushort* __restrict__ out, int N) {
  const int node = blockIdx.x * 4 + (threadIdx.x >> 6);
  if (node >= N) return;
  const int lane = threadIdx.x & 63;
  const int beg = row_ptr[node];
  const int end = row_ptr[node + 1];
  const ushort* hp = h + lane * 2;
  float ax = 0.f, ay = 0.f, bx = 0.f, by = 0.f;
  int e = beg;
  for (; e + 7 < end; e += 8) {
    const int s0 = esrc[e + 0];
    const int s1 = esrc[e + 1];
    const int s2 = esrc[e + 2];
    const int s3 = esrc[e + 3];
    const int s4 = esrc[e + 4];
    const int s5 = esrc[e + 5];
    const int s6 = esrc[e + 6];
    const int s7 = esrc[e + 7];
    const unsigned int u0 = *reinterpret_cast<const unsigned int*>(hp + (size_t)s0 * D);
    const unsigned int u1 = *reinterpret_cast<const unsigned int*>(hp + (size_t)s1 * D);
    const unsigned int u2 = *reinterpret_cast<const unsigned int*>(hp + (size_t)s2 * D);
    const unsigned int u3 = *reinterpret_cast<const unsigned int*>(hp + (size_t)s3 * D);
    const unsigned int u4 = *reinterpret_cast<const unsigned int*>(hp + (size_t)s4 * D);
    const unsigned int u5 = *reinterpret_cast<const unsigned int*>(hp + (size_t)s5 * D);
    const unsigned int u6 = *reinterpret_cast<const unsigned int*>(hp + (size_t)s6 * D);
    const unsigned int u7 = *reinterpret_cast<const unsigned int*>(hp + (size_t)s7 * D);
    ax += __uint_as_float(u0 << 16) + __uint_as_float(u1 << 16);
    ay += __uint_as_float(u0 & 0xffff0000u) + __uint_as_float(u1 & 0xffff0000u);
    bx += __uint_as_float(u2 << 16) + __uint_as_float(u3 << 16);
    by += __uint_as_float(u2 & 0xffff0000u) + __uint_as_float(u3 & 0xffff0000u);
    ax += __uint_as_float(u4 << 16) + __uint_as_float(u5 << 16);
    ay += __uint_as_float(u4 & 0xffff0000u) + __uint_as_float(u5 & 0xffff0000u);
    bx += __uint_as_float(u6 << 16) + __uint_as_float(u7 << 16);
    by += __uint_as_float(u6 & 0xffff0000u) + __uint_as_float(u7 & 0xffff0000u);
  }
  if (e + 3 < end) {
    const int s0 = esrc[e + 0];
    const int s1 = esrc[e + 1];
    const int s2 = esrc[e + 2];
    const int s3 = esrc[e + 3];
    const unsigned int u0 = *reinterpret_cast<const unsigned int*>(hp + (size_t)s0 * D);
    const unsigned int u1 = *reinterpret_cast<const unsigned int*>(hp + (size_t)s1 * D);
    const unsigned int u2 = *reinterpret_cast<const unsigned int*>(hp + (size_t)s2 * D);
    const unsigned int u3 = *reinterpret_cast<const unsigned int*>(hp + (size_t)s3 * D);
    ax += __uint_as_float(u0 << 16) + __uint_as_float(u1 << 16);
    ay += __uint_as_float(u0 & 0xffff0000u) + __uint_as_float(u1 & 0xffff0000u);
    bx += __uint_as_float(u2 << 16) + __uint_as_float(u3 << 16);
    by += __uint_as_float(u2 & 0xffff0000u) + __uint_as_float(u3 & 0xffff0000u);
    e += 4;
  }
  if (e + 1 < end) {
    const int s0 = esrc[e + 0];
    const int s1 = esrc[e + 1];
    const unsigned int u0 = *reinterpret_cast<const unsigned int*>(hp + (size_t)s0 * D);
    const unsigned int u1 = *reinterpret_cast<const unsigned int*>(hp + (size_t)s1 * D);
    ax += __uint_as_float(u0 << 16) + __uint_as_float(u1 << 16);
    ay += __uint_as_float(u0 & 0xffff0000u) + __uint_as_float(u1 & 0xffff0000u);
    e += 2;
  }
  if (e < end) {
    const unsigned int u0 = *reinterpret_cast<const unsigned int*>(hp + (size_t)esrc[e] * D);
    ax += __uint_as_float(u0 << 16);
    ay += __uint_as_float(u0 & 0xffff0000u);
  }
  ax += bx;
  ay += by;
  const float iv = inv[node];
  union { __bf16 b[2]; unsigned int u; } p;
  p.b[0] = (__bf16)(ax * iv);
  p.b[1] = (__bf16)(ay * iv);
  *reinterpret_cast<unsigned int*>(out + (size_t)node * D + lane * 2) = p.u;
}

// ---- MFMA GEMM (layer 1): h1 = relu(A @ W^T + bias) ----------------------

__global__ __launch_bounds__(256) void k_gemm_mfma(const ushort* __restrict__ A,
                                                   const ushort* __restrict__ Wb,
                                                   const float* __restrict__ bias,
                                                   ushort* __restrict__ Hout, int N) {
  const int wave = threadIdx.x >> 6;
  const int lane = threadIdx.x & 63;
  const int l15 = lane & 15;
  const int quad = lane >> 4;

  B8 bfrag[2][4];
  float bv[2];
#pragma unroll
  for (int t = 0; t < 2; ++t) {
    const int n = wave * 32 + t * 16 + l15;
    bv[t] = bias[n];
#pragma unroll
    for (int ks = 0; ks < 4; ++ks)
      bfrag[t][ks].u = *reinterpret_cast<const uint4*>(Wb + n * D + ks * 32 + quad * 8);
  }

  const int mtiles = N >> 4;
  for (int mt = blockIdx.x; mt < mtiles; mt += gridDim.x) {
    const ushort* ap = A + (size_t)(mt * 16 + l15) * D + quad * 8;
    B8 a0, a1, a2, a3;
    a0.u = *reinterpret_cast<const uint4*>(ap);
    a1.u = *reinterpret_cast<const uint4*>(ap + 32);
    a2.u = *reinterpret_cast<const uint4*>(ap + 64);
    a3.u = *reinterpret_cast<const uint4*>(ap + 96);
#pragma unroll
    for (int t = 0; t < 2; ++t) {
      f32x4 acc = {0.f, 0.f, 0.f, 0.f};
      acc = __builtin_amdgcn_mfma_f32_16x16x32_bf16(a0.v, bfrag[t][0].v, acc, 0, 0, 0);
      acc = __builtin_amdgcn_mfma_f32_16x16x32_bf16(a1.v, bfrag[t][1].v, acc, 0, 0, 0);
      acc = __builtin_amdgcn_mfma_f32_16x16x32_bf16(a2.v, bfrag[t][2].v, acc, 0, 0, 0);
      acc = __builtin_amdgcn_mfma_f32_16x16x32_bf16(a3.v, bfrag[t][3].v, acc, 0, 0, 0);
      const int col = wave * 32 + t * 16 + l15;
#pragma unroll
      for (int r = 0; r < 4; ++r) {
        const int row = mt * 16 + quad * 4 + r;
        const float v = fmaxf(acc[r] + bv[t], 0.f);
        union { __bf16 b; ushort s; } c;
        c.b = (__bf16)v;
        Hout[(size_t)row * D + col] = c.s;
      }
    }
  }
}

// ---- fused layer-2 GEMM + logits + log_softmax ---------------------------
// Phase 1: wave w computes h2 cols [w*32,w*32+32) from agg2 (relu), writes the
// bf16 16x128 tile to LDS (stride 136 -> 16B-aligned A-frag reads).
// Phase 2: wave w computes logit cols [w*16,w*16+16) = h1@Wl1^T + h2@Wl2^T,
// tile -> LDS -> per-row wave softmax -> coalesced f32 store. h2 never
// touches global memory.

__global__ __launch_bounds__(256) void k_gemm2_logits(const ushort* __restrict__ A2,
                                                      const ushort* __restrict__ H1,
                                                      const ushort* __restrict__ W2b,
                                                      const float* __restrict__ b2,
                                                      const ushort* __restrict__ Wlb,
                                                      const float* __restrict__ bl,
                                                      float* __restrict__ out, int N) {
  __shared__ ushort H2t[16][136];
  __shared__ float L[16][NCLS + 4];
  const int wave = threadIdx.x >> 6;
  const int lane = threadIdx.x & 63;
  const int l15 = lane & 15;
  const int quad = lane >> 4;

  // W2 B-frags (h2 cols [wave*32, wave*32+32))
  B8 bfrag2[2][4];
  float bv2[2];
#pragma unroll
  for (int t = 0; t < 2; ++t) {
    const int n = wave * 32 + t * 16 + l15;
    bv2[t] = b2[n];
#pragma unroll
    for (int ks = 0; ks < 4; ++ks)
      bfrag2[t][ks].u = *reinterpret_cast<const uint4*>(W2b + n * D + ks * 32 + quad * 8);
  }
  // Wl B-frags (logit cols [wave*16, wave*16+16); k = 0..256)
  B8 bfragL[8];
  const int nl = wave * 16 + l15;
  const float bbl = bl[nl];
#pragma unroll
  for (int ks = 0; ks < 8; ++ks)
    bfragL[ks].u = *reinterpret_cast<const uint4*>(Wlb + nl * (2 * D) + ks * 32 + quad * 8);

  const int mtiles = N >> 4;
  for (int mt = blockIdx.x; mt < mtiles; mt += gridDim.x) {
    // ---- phase 1: h2 tile ----
    const ushort* ap = A2 + (size_t)(mt * 16 + l15) * D + quad * 8;
    B8 a0, a1, a2, a3;
    a0.u = *reinterpret_cast<const uint4*>(ap);
    a1.u = *reinterpret_cast<const uint4*>(ap + 32);
    a2.u = *reinterpret_cast<const uint4*>(ap + 64);
    a3.u = *reinterpret_cast<const uint4*>(ap + 96);
#pragma unroll
    for (int t = 0; t < 2; ++t) {
      f32x4 acc = {0.f, 0.f, 0.f, 0.f};
      acc = __builtin_amdgcn_mfma_f32_16x16x32_bf16(a0.v, bfrag2[t][0].v, acc, 0, 0, 0);
      acc = __builtin_amdgcn_mfma_f32_16x16x32_bf16(a1.v, bfrag2[t][1].v, acc, 0, 0, 0);
      acc = __builtin_amdgcn_mfma_f32_16x16x32_bf16(a2.v, bfrag2[t][2].v, acc, 0, 0, 0);
      acc = __builtin_amdgcn_mfma_f32_16x16x32_bf16(a3.v, bfrag2[t][3].v, acc, 0, 0, 0);
      const int col = wave * 32 + t * 16 + l15;
#pragma unroll
      for (int r = 0; r < 4; ++r) {
        const float v = fmaxf(acc[r] + bv2[t], 0.f);
        union { __bf16 b; ushort s; } c;
        c.b = (__bf16)v;
        H2t[quad * 4 + r][col] = c.s;
      }
    }
    __syncthreads();
    // ---- phase 2: logits ----
    const size_t rb = (size_t)(mt * 16 + l15) * D + quad * 8;
    f32x4 acc = {0.f, 0.f, 0.f, 0.f};
    B8 a;
#pragma unroll
    for (int ks = 0; ks < 4; ++ks) {
      a.u = *reinterpret_cast<const uint4*>(H1 + rb + ks * 32);
      acc = __builtin_amdgcn_mfma_f32_16x16x32_bf16(a.v, bfragL[ks].v, acc, 0, 0, 0);
    }
#pragma unroll
    for (int ks = 0; ks < 4; ++ks) {
      a.u = *reinterpret_cast<const uint4*>(&H2t[l15][ks * 32 + quad * 8]);
      acc = __builtin_amdgcn_mfma_f32_16x16x32_bf16(a.v, bfragL[4 + ks].v, acc, 0, 0, 0);
    }
#pragma unroll
    for (int r = 0; r < 4; ++r)
      L[quad * 4 + r][wave * 16 + l15] = acc[r] + bbl;
    __syncthreads();
    // ---- softmax ----
#pragma unroll
    for (int r = 0; r < 4; ++r) {
      const int row = wave * 4 + r;
      float v = L[row][lane];
      float m = v;
#pragma unroll
      for (int off = 32; off > 0; off >>= 1) m = fmaxf(m, __shfl_xor(m, off));
      float e = __expf(v - m);
#pragma unroll
      for (int off = 32; off > 0; off >>= 1) e += __shfl_xor(e, off);
      out[(size_t)(mt * 16 + row) * NCLS + lane] = v - m - __logf(e);
    }
    __syncthreads();
  }
}

// ---- driver --------------------------------------------------------------

extern "C" void kernel_launch(void* const* d_in, const int* in_sizes, int n_in,
                              void* d_out, int out_size, void* d_ws, size_t ws_size,
                              hipStream_t stream) {
  const float* feat = (const float*)d_in[0];
  const int* src = (const int*)d_in[1];
  const int* dst = (const int*)d_in[2];
  const float* W1 = (const float*)d_in[3];
  const float* b1 = (const float*)d_in[4];
  const float* W2 = (const float*)d_in[5];
  const float* b2 = (const float*)d_in[6];
  const float* Wl = (const float*)d_in[7];
  const float* bl = (const float*)d_in[8];
  float* out = (float*)d_out;

  const int N = in_sizes[0] / D;  // 100000
  const int E = in_sizes[1];      // 1600000
  const int NB = (N + 127) >> BSH;  // 782

  // workspace layout
  float* ws = (float*)d_ws;
  float* inv = ws;                          // N
  ushort* featb = (ushort*)(inv + N);       // N*D
  ushort* scratch = featb + (size_t)N * D;  // N*D (ebuck aliases, then agg)
  ushort* h1b = scratch + (size_t)N * D;    // N*D
  int* row_ptr = (int*)(h1b + (size_t)N * D);  // N+1
  int* esrc = row_ptr + N + 1;              // E
  int* bcnt = esrc + E;                     // NBMAX
  int* bbase = bcnt + NBMAX;                // NBMAX+1
  int* bcur = bbase + NBMAX + 1;            // NBMAX
  ushort* W1b = (ushort*)(bcur + NBMAX);    // D*D
  ushort* W2b = W1b + D * D;                // D*D
  ushort* Wlb = W2b + D * D;                // 2*D*NCLS
  int* ebuck = (int*)scratch;               // E ints, dead after k_bbuild

  hipMemsetAsync(bcnt, 0, NBMAX * sizeof(int), stream);

  // bf16 copies: features + weights (one launch)
  const int n8 = N * D / 8;
  const int prepTot = n8 + 2 * (D * D / 8) + (2 * D * NCLS / 8);
  k_prep<<<(prepTot + 255) / 256, 256, 0, stream>>>(feat, W1, W2, Wl,
                                                    featb, W1b, W2b, Wlb, n8);

  // bucketed CSR build
  k_bhist<<<256, 256, 0, stream>>>(dst, bcnt, E, NB);
  k_bscan<<<1, 1024, 0, stream>>>(bcnt, bbase, bcur, NB, E);
  k_bscatter<<<(E + CCHUNK - 1) / CCHUNK, 256, 0, stream>>>(src, dst, bcur, ebuck, E, NB);
  k_bbuild<<<NB, 256, 0, stream>>>(ebuck, bbase, row_ptr, esrc, inv, N, E);

  const int gatherBlocks = (N + 3) / 4;
  ushort* aggb = scratch;

  // layer 1
  k_gather_mean<<<gatherBlocks, 256, 0, stream>>>(featb, row_ptr, esrc, inv, aggb, N);
  k_gemm_mfma<<<2048, 256, 0, stream>>>(aggb, W1b, b1, h1b, N);

  // layer 2 gather + fused GEMM/logits/softmax
  k_gather_mean<<<gatherBlocks, 256, 0, stream>>>(h1b, row_ptr, esrc, inv, aggb, N);
  k_gemm2_logits<<<2048, 256, 0, stream>>>(aggb, h1b, W2b, b2, Wlb, bl, out, N);
}

// Round 8
// 366.789 us; speedup vs baseline: 1.2331x; 1.0160x over previous
//
#include <hip/hip_runtime.h>
#include <stdint.h>

#define D 128
#define NCLS 64
#define BSH 7       // 128 nodes per bucket
#define NBMAX 1024  // max buckets (N <= 131072)
#define CCHUNK 4096 // edges per k_bscatter block

typedef __bf16 bf16x8 __attribute__((ext_vector_type(8)));
typedef float f32x4 __attribute__((ext_vector_type(4)));

union B8 { uint4 u; bf16x8 v; };

// ---- f32 -> bf16 bulk convert: features + all weights + bcnt zero --------

__global__ __launch_bounds__(256) void k_prep(const float* __restrict__ feat,
                                              const float* __restrict__ W1,
                                              const float* __restrict__ W2,
                                              const float* __restrict__ Wl,
                                              ushort* __restrict__ featb,
                                              ushort* __restrict__ W1b,
                                              ushort* __restrict__ W2b,
                                              ushort* __restrict__ Wlb,
                                              int* __restrict__ bcnt, int n8feat) {
  const int n1 = D * D / 8;
  const int nl = 2 * D * NCLS / 8;
  int t = blockIdx.x * 256 + threadIdx.x;
  if (t < NBMAX) bcnt[t] = 0;
  const float* xp; ushort* yp; int idx;
  if (t < n8feat) { xp = feat; yp = featb; idx = t; }
  else {
    t -= n8feat;
    if (t < n1) { xp = W1; yp = W1b; idx = t; }
    else if (t < 2 * n1) { xp = W2; yp = W2b; idx = t - n1; }
    else if (t < 2 * n1 + nl) { xp = Wl; yp = Wlb; idx = t - 2 * n1; }
    else return;
  }
  const float4 a = reinterpret_cast<const float4*>(xp)[idx * 2 + 0];
  const float4 b = reinterpret_cast<const float4*>(xp)[idx * 2 + 1];
  union { __bf16 h[8]; uint4 u; } p;
  p.h[0] = (__bf16)a.x; p.h[1] = (__bf16)a.y; p.h[2] = (__bf16)a.z; p.h[3] = (__bf16)a.w;
  p.h[4] = (__bf16)b.x; p.h[5] = (__bf16)b.y; p.h[6] = (__bf16)b.z; p.h[7] = (__bf16)b.w;
  reinterpret_cast<uint4*>(yp)[idx] = p.u;
}

// ---- bucketed CSR build --------------------------------------------------

__global__ __launch_bounds__(256) void k_bhist(const int* __restrict__ dst,
                                               int* __restrict__ bcnt, int E, int NB) {
  __shared__ int h[NBMAX];
  for (int i = threadIdx.x; i < NB; i += 256) h[i] = 0;
  __syncthreads();
  for (int e = blockIdx.x * 256 + threadIdx.x; e < E; e += gridDim.x * 256)
    atomicAdd(&h[dst[e] >> BSH], 1);
  __syncthreads();
  for (int i = threadIdx.x; i < NB; i += 256) {
    int c = h[i];
    if (c) atomicAdd(&bcnt[i], c);
  }
}

__global__ __launch_bounds__(1024) void k_bscan(const int* __restrict__ bcnt,
                                                int* __restrict__ bbase,
                                                int* __restrict__ bcur, int NB, int E) {
  __shared__ int sm[NBMAX];
  const int tid = threadIdx.x;
  int v = (tid < NB) ? bcnt[tid] : 0;
  sm[tid] = v;
  __syncthreads();
  for (int off = 1; off < NBMAX; off <<= 1) {
    int t = (tid >= off) ? sm[tid - off] : 0;
    __syncthreads();
    sm[tid] += t;
    __syncthreads();
  }
  if (tid < NB) {
    bbase[tid] = sm[tid] - v;
    bcur[tid] = sm[tid] - v;
  }
  if (tid == 0) bbase[NB] = E;
}

__global__ __launch_bounds__(256) void k_bscatter(const int* __restrict__ src,
                                                  const int* __restrict__ dst,
                                                  int* __restrict__ bcur,
                                                  int* __restrict__ ebuck, int E, int NB) {
  __shared__ int h[NBMAX];
  __shared__ int base[NBMAX];
  const int beg = blockIdx.x * CCHUNK;
  const int end = min(beg + CCHUNK, E);
  for (int i = threadIdx.x; i < NB; i += 256) h[i] = 0;
  __syncthreads();
  for (int e = beg + threadIdx.x; e < end; e += 256)
    atomicAdd(&h[dst[e] >> BSH], 1);
  __syncthreads();
  for (int i = threadIdx.x; i < NB; i += 256) {
    int c = h[i];
    base[i] = c ? atomicAdd(&bcur[i], c) : 0;
    h[i] = 0;  // becomes local rank cursor
  }
  __syncthreads();
  for (int e = beg + threadIdx.x; e < end; e += 256) {
    const int d = dst[e];
    const int b = d >> BSH;
    const int r = atomicAdd(&h[b], 1);
    ebuck[base[b] + r] = (src[e] << BSH) | (d & 127);
  }
}

__global__ __launch_bounds__(256) void k_bbuild(const int* __restrict__ ebuck,
                                                const int* __restrict__ bbase,
                                                int* __restrict__ row_ptr,
                                                int* __restrict__ esrc,
                                                float* __restrict__ inv, int N, int E) {
  __shared__ int cnt[128], s[128], cur[128];
  const int b = blockIdx.x;
  const int n0 = b << BSH;
  const int nn = min(128, N - n0);
  const int beg = bbase[b], end = bbase[b + 1];
  const int tid = threadIdx.x;
  if (tid < 128) cnt[tid] = 0;
  __syncthreads();
  for (int e = beg + tid; e < end; e += 256)
    atomicAdd(&cnt[ebuck[e] & 127], 1);
  __syncthreads();
  if (tid < 128) s[tid] = cnt[tid];
  __syncthreads();
  for (int off = 1; off < 128; off <<= 1) {
    int t = (tid < 128 && tid >= off) ? s[tid - off] : 0;
    __syncthreads();
    if (tid < 128) s[tid] += t;
    __syncthreads();
  }
  if (tid < 128) {
    const int ex = s[tid] - cnt[tid];
    cur[tid] = ex;
    if (tid < nn) {
      row_ptr[n0 + tid] = beg + ex;
      inv[n0 + tid] = 1.0f / fmaxf((float)cnt[tid], 1.0f);
    }
  }
  if (b == 0 && tid == 0) row_ptr[N] = E;
  __syncthreads();
  for (int e = beg + tid; e < end; e += 256) {
    const int p = ebuck[e];
    const int r = atomicAdd(&cur[p & 127], 1);
    esrc[beg + r] = p >> BSH;
  }
}

// ---- mean aggregation, quad-gather: one wave per node --------------------
// Quad q (16 lanes) handles edge e+q; lane loads uint4 = 8 bf16 feats.
// One VMEM instr covers 4 edge rows (1 KB). Main loop: 16 edges = 4
// independent 1 KB loads in flight. Cross-quad reduce via 2 shfl_xor.

__device__ __forceinline__ void acc8(float* acc, const uint4& u) {
  acc[0] += __uint_as_float(u.x << 16);
  acc[1] += __uint_as_float(u.x & 0xffff0000u);
  acc[2] += __uint_as_float(u.y << 16);
  acc[3] += __uint_as_float(u.y & 0xffff0000u);
  acc[4] += __uint_as_float(u.z << 16);
  acc[5] += __uint_as_float(u.z & 0xffff0000u);
  acc[6] += __uint_as_float(u.w << 16);
  acc[7] += __uint_as_float(u.w & 0xffff0000u);
}

__global__ __launch_bounds__(256) void k_gather_mean(const ushort* __restrict__ h,
                                                     const int* __restrict__ row_ptr,
                                                     const int* __restrict__ esrc,
                                                     const float* __restrict__ inv,
                                                     ushort* __restrict__ out, int N) {
  const int node = blockIdx.x * 4 + (threadIdx.x >> 6);
  if (node >= N) return;
  const int lane = threadIdx.x & 63;
  const int q = lane >> 4;   // quad -> edge offset
  const int w = lane & 15;   // feature group [w*8, w*8+8)
  const int beg = row_ptr[node];
  const int end = row_ptr[node + 1];
  const ushort* hp = h + w * 8;
  float acc[8] = {0.f, 0.f, 0.f, 0.f, 0.f, 0.f, 0.f, 0.f};
  int e = beg;
  for (; e + 15 < end; e += 16) {
    const int s0 = esrc[e + q];
    const int s1 = esrc[e + 4 + q];
    const int s2 = esrc[e + 8 + q];
    const int s3 = esrc[e + 12 + q];
    const uint4 u0 = *reinterpret_cast<const uint4*>(hp + (size_t)s0 * D);
    const uint4 u1 = *reinterpret_cast<const uint4*>(hp + (size_t)s1 * D);
    const uint4 u2 = *reinterpret_cast<const uint4*>(hp + (size_t)s2 * D);
    const uint4 u3 = *reinterpret_cast<const uint4*>(hp + (size_t)s3 * D);
    acc8(acc, u0);
    acc8(acc, u1);
    acc8(acc, u2);
    acc8(acc, u3);
  }
  if (e + 7 < end) {
    const int s0 = esrc[e + q];
    const int s1 = esrc[e + 4 + q];
    const uint4 u0 = *reinterpret_cast<const uint4*>(hp + (size_t)s0 * D);
    const uint4 u1 = *reinterpret_cast<const uint4*>(hp + (size_t)s1 * D);
    acc8(acc, u0);
    acc8(acc, u1);
    e += 8;
  }
  if (e + 3 < end) {
    const int s0 = esrc[e + q];
    const uint4 u0 = *reinterpret_cast<const uint4*>(hp + (size_t)s0 * D);
    acc8(acc, u0);
    e += 4;
  }
  if (e + q < end) {
    const int s0 = esrc[e + q];
    const uint4 u0 = *reinterpret_cast<const uint4*>(hp + (size_t)s0 * D);
    acc8(acc, u0);
  }
  // reduce across quads (all lanes participate)
#pragma unroll
  for (int i = 0; i < 8; ++i) {
    acc[i] += __shfl_xor(acc[i], 16);
    acc[i] += __shfl_xor(acc[i], 32);
  }
  if (q == 0) {
    const float iv = inv[node];
    union { __bf16 b[8]; uint4 u; } p;
#pragma unroll
    for (int i = 0; i < 8; ++i) p.b[i] = (__bf16)(acc[i] * iv);
    *reinterpret_cast<uint4*>(out + (size_t)node * D + w * 8) = p.u;
  }
}

// ---- MFMA GEMM (layer 1): h1 = relu(A @ W^T + bias), 2 tiles/iter --------

__device__ __forceinline__ void gemm_tile16(const ushort* __restrict__ A,
                                            const B8 bfrag[2][4], const float bv[2],
                                            ushort* __restrict__ Hout, int mt,
                                            int l15, int quad, int wave) {
  const ushort* ap = A + (size_t)(mt * 16 + l15) * D + quad * 8;
  B8 a0, a1, a2, a3;
  a0.u = *reinterpret_cast<const uint4*>(ap);
  a1.u = *reinterpret_cast<const uint4*>(ap + 32);
  a2.u = *reinterpret_cast<const uint4*>(ap + 64);
  a3.u = *reinterpret_cast<const uint4*>(ap + 96);
#pragma unroll
  for (int t = 0; t < 2; ++t) {
    f32x4 acc = {0.f, 0.f, 0.f, 0.f};
    acc = __builtin_amdgcn_mfma_f32_16x16x32_bf16(a0.v, bfrag[t][0].v, acc, 0, 0, 0);
    acc = __builtin_amdgcn_mfma_f32_16x16x32_bf16(a1.v, bfrag[t][1].v, acc, 0, 0, 0);
    acc = __builtin_amdgcn_mfma_f32_16x16x32_bf16(a2.v, bfrag[t][2].v, acc, 0, 0, 0);
    acc = __builtin_amdgcn_mfma_f32_16x16x32_bf16(a3.v, bfrag[t][3].v, acc, 0, 0, 0);
    const int col = wave * 32 + t * 16 + l15;
#pragma unroll
    for (int r = 0; r < 4; ++r) {
      const int row = mt * 16 + quad * 4 + r;
      const float v = fmaxf(acc[r] + bv[t], 0.f);
      union { __bf16 b; ushort s; } c;
      c.b = (__bf16)v;
      Hout[(size_t)row * D + col] = c.s;
    }
  }
}

__global__ __launch_bounds__(256) void k_gemm_mfma(const ushort* __restrict__ A,
                                                   const ushort* __restrict__ Wb,
                                                   const float* __restrict__ bias,
                                                   ushort* __restrict__ Hout, int N) {
  const int wave = threadIdx.x >> 6;
  const int lane = threadIdx.x & 63;
  const int l15 = lane & 15;
  const int quad = lane >> 4;

  B8 bfrag[2][4];
  float bv[2];
#pragma unroll
  for (int t = 0; t < 2; ++t) {
    const int n = wave * 32 + t * 16 + l15;
    bv[t] = bias[n];
#pragma unroll
    for (int ks = 0; ks < 4; ++ks)
      bfrag[t][ks].u = *reinterpret_cast<const uint4*>(Wb + n * D + ks * 32 + quad * 8);
  }

  const int mtiles = N >> 4;
  const int pairs = mtiles >> 1;
  for (int p = blockIdx.x; p < pairs; p += gridDim.x) {
    gemm_tile16(A, bfrag, bv, Hout, p * 2 + 0, l15, quad, wave);
    gemm_tile16(A, bfrag, bv, Hout, p * 2 + 1, l15, quad, wave);
  }
  if ((mtiles & 1) && blockIdx.x == 0)
    gemm_tile16(A, bfrag, bv, Hout, mtiles - 1, l15, quad, wave);
}

// ---- fused layer-2 GEMM + logits + log_softmax ---------------------------

__global__ __launch_bounds__(256) void k_gemm2_logits(const ushort* __restrict__ A2,
                                                      const ushort* __restrict__ H1,
                                                      const ushort* __restrict__ W2b,
                                                      const float* __restrict__ b2,
                                                      const ushort* __restrict__ Wlb,
                                                      const float* __restrict__ bl,
                                                      float* __restrict__ out, int N) {
  __shared__ ushort H2t[16][136];
  __shared__ float L[16][NCLS + 4];
  const int wave = threadIdx.x >> 6;
  const int lane = threadIdx.x & 63;
  const int l15 = lane & 15;
  const int quad = lane >> 4;

  B8 bfrag2[2][4];
  float bv2[2];
#pragma unroll
  for (int t = 0; t < 2; ++t) {
    const int n = wave * 32 + t * 16 + l15;
    bv2[t] = b2[n];
#pragma unroll
    for (int ks = 0; ks < 4; ++ks)
      bfrag2[t][ks].u = *reinterpret_cast<const uint4*>(W2b + n * D + ks * 32 + quad * 8);
  }
  B8 bfragL[8];
  const int nl = wave * 16 + l15;
  const float bbl = bl[nl];
#pragma unroll
  for (int ks = 0; ks < 8; ++ks)
    bfragL[ks].u = *reinterpret_cast<const uint4*>(Wlb + nl * (2 * D) + ks * 32 + quad * 8);

  const int mtiles = N >> 4;
  for (int mt = blockIdx.x; mt < mtiles; mt += gridDim.x) {
    // ---- phase 1: h2 tile ----
    const ushort* ap = A2 + (size_t)(mt * 16 + l15) * D + quad * 8;
    B8 a0, a1, a2, a3;
    a0.u = *reinterpret_cast<const uint4*>(ap);
    a1.u = *reinterpret_cast<const uint4*>(ap + 32);
    a2.u = *reinterpret_cast<const uint4*>(ap + 64);
    a3.u = *reinterpret_cast<const uint4*>(ap + 96);
#pragma unroll
    for (int t = 0; t < 2; ++t) {
      f32x4 acc = {0.f, 0.f, 0.f, 0.f};
      acc = __builtin_amdgcn_mfma_f32_16x16x32_bf16(a0.v, bfrag2[t][0].v, acc, 0, 0, 0);
      acc = __builtin_amdgcn_mfma_f32_16x16x32_bf16(a1.v, bfrag2[t][1].v, acc, 0, 0, 0);
      acc = __builtin_amdgcn_mfma_f32_16x16x32_bf16(a2.v, bfrag2[t][2].v, acc, 0, 0, 0);
      acc = __builtin_amdgcn_mfma_f32_16x16x32_bf16(a3.v, bfrag2[t][3].v, acc, 0, 0, 0);
      const int col = wave * 32 + t * 16 + l15;
#pragma unroll
      for (int r = 0; r < 4; ++r) {
        const float v = fmaxf(acc[r] + bv2[t], 0.f);
        union { __bf16 b; ushort s; } c;
        c.b = (__bf16)v;
        H2t[quad * 4 + r][col] = c.s;
      }
    }
    __syncthreads();
    // ---- phase 2: logits ----
    const size_t rb = (size_t)(mt * 16 + l15) * D + quad * 8;
    f32x4 acc = {0.f, 0.f, 0.f, 0.f};
    B8 a;
#pragma unroll
    for (int ks = 0; ks < 4; ++ks) {
      a.u = *reinterpret_cast<const uint4*>(H1 + rb + ks * 32);
      acc = __builtin_amdgcn_mfma_f32_16x16x32_bf16(a.v, bfragL[ks].v, acc, 0, 0, 0);
    }
#pragma unroll
    for (int ks = 0; ks < 4; ++ks) {
      a.u = *reinterpret_cast<const uint4*>(&H2t[l15][ks * 32 + quad * 8]);
      acc = __builtin_amdgcn_mfma_f32_16x16x32_bf16(a.v, bfragL[4 + ks].v, acc, 0, 0, 0);
    }
#pragma unroll
    for (int r = 0; r < 4; ++r)
      L[quad * 4 + r][wave * 16 + l15] = acc[r] + bbl;
    __syncthreads();
    // ---- softmax ----
#pragma unroll
    for (int r = 0; r < 4; ++r) {
      const int row = wave * 4 + r;
      float v = L[row][lane];
      float m = v;
#pragma unroll
      for (int off = 32; off > 0; off >>= 1) m = fmaxf(m, __shfl_xor(m, off));
      float e = __expf(v - m);
#pragma unroll
      for (int off = 32; off > 0; off >>= 1) e += __shfl_xor(e, off);
      out[(size_t)(mt * 16 + row) * NCLS + lane] = v - m - __logf(e);
    }
    __syncthreads();
  }
}

// ---- driver --------------------------------------------------------------

extern "C" void kernel_launch(void* const* d_in, const int* in_sizes, int n_in,
                              void* d_out, int out_size, void* d_ws, size_t ws_size,
                              hipStream_t stream) {
  const float* feat = (const float*)d_in[0];
  const int* src = (const int*)d_in[1];
  const int* dst = (const int*)d_in[2];
  const float* W1 = (const float*)d_in[3];
  const float* b1 = (const float*)d_in[4];
  const float* W2 = (const float*)d_in[5];
  const float* b2 = (const float*)d_in[6];
  const float* Wl = (const float*)d_in[7];
  const float* bl = (const float*)d_in[8];
  float* out = (float*)d_out;

  const int N = in_sizes[0] / D;  // 100000
  const int E = in_sizes[1];      // 1600000
  const int NB = (N + 127) >> BSH;  // 782

  // workspace layout
  float* ws = (float*)d_ws;
  float* inv = ws;                          // N
  ushort* featb = (ushort*)(inv + N);       // N*D
  ushort* scratch = featb + (size_t)N * D;  // N*D (ebuck aliases, then agg)
  ushort* h1b = scratch + (size_t)N * D;    // N*D
  int* row_ptr = (int*)(h1b + (size_t)N * D);  // N+1
  int* esrc = row_ptr + N + 1;              // E
  int* bcnt = esrc + E;                     // NBMAX
  int* bbase = bcnt + NBMAX;                // NBMAX+1
  int* bcur = bbase + NBMAX + 1;            // NBMAX
  ushort* W1b = (ushort*)(bcur + NBMAX);    // D*D
  ushort* W2b = W1b + D * D;                // D*D
  ushort* Wlb = W2b + D * D;                // 2*D*NCLS
  int* ebuck = (int*)scratch;               // E ints, dead after k_bbuild

  // bf16 copies + bcnt zero (one launch)
  const int n8 = N * D / 8;
  const int prepTot = n8 + 2 * (D * D / 8) + (2 * D * NCLS / 8);
  k_prep<<<(prepTot + 255) / 256, 256, 0, stream>>>(feat, W1, W2, Wl,
                                                    featb, W1b, W2b, Wlb, bcnt, n8);

  // bucketed CSR build
  k_bhist<<<256, 256, 0, stream>>>(dst, bcnt, E, NB);
  k_bscan<<<1, 1024, 0, stream>>>(bcnt, bbase, bcur, NB, E);
  k_bscatter<<<(E + CCHUNK - 1) / CCHUNK, 256, 0, stream>>>(src, dst, bcur, ebuck, E, NB);
  k_bbuild<<<NB, 256, 0, stream>>>(ebuck, bbase, row_ptr, esrc, inv, N, E);

  const int gatherBlocks = (N + 3) / 4;
  ushort* aggb = scratch;

  // layer 1
  k_gather_mean<<<gatherBlocks, 256, 0, stream>>>(featb, row_ptr, esrc, inv, aggb, N);
  k_gemm_mfma<<<2048, 256, 0, stream>>>(aggb, W1b, b1, h1b, N);

  // layer 2 gather + fused GEMM/logits/softmax
  k_gather_mean<<<gatherBlocks, 256, 0, stream>>>(h1b, row_ptr, esrc, inv, aggb, N);
  k_gemm2_logits<<<2048, 256, 0, stream>>>(aggb, h1b, W2b, b2, Wlb, bl, out, N);
}

// Round 9
// 366.350 us; speedup vs baseline: 1.2346x; 1.0012x over previous
//
#include <hip/hip_runtime.h>
#include <stdint.h>

#define D 128
#define NCLS 64
#define BSH 7       // 128 nodes per bucket
#define NBMAX 1024  // max buckets (N <= 131072)
#define CCHUNK 4096 // edges per k_bscatter block

typedef __bf16 bf16x8 __attribute__((ext_vector_type(8)));
typedef float f32x4 __attribute__((ext_vector_type(4)));
typedef float f32x2 __attribute__((ext_vector_type(2)));

union B8 { uint4 u; bf16x8 v; };

// ---- f32 -> bf16 bulk convert: features + all weights + bcnt zero --------

__global__ __launch_bounds__(256) void k_prep(const float* __restrict__ feat,
                                              const float* __restrict__ W1,
                                              const float* __restrict__ W2,
                                              const float* __restrict__ Wl,
                                              ushort* __restrict__ featb,
                                              ushort* __restrict__ W1b,
                                              ushort* __restrict__ W2b,
                                              ushort* __restrict__ Wlb,
                                              int* __restrict__ bcnt, int n8feat) {
  const int n1 = D * D / 8;
  const int nl = 2 * D * NCLS / 8;
  int t = blockIdx.x * 256 + threadIdx.x;
  if (t < NBMAX) bcnt[t] = 0;
  const float* xp; ushort* yp; int idx;
  if (t < n8feat) { xp = feat; yp = featb; idx = t; }
  else {
    t -= n8feat;
    if (t < n1) { xp = W1; yp = W1b; idx = t; }
    else if (t < 2 * n1) { xp = W2; yp = W2b; idx = t - n1; }
    else if (t < 2 * n1 + nl) { xp = Wl; yp = Wlb; idx = t - 2 * n1; }
    else return;
  }
  const float4 a = reinterpret_cast<const float4*>(xp)[idx * 2 + 0];
  const float4 b = reinterpret_cast<const float4*>(xp)[idx * 2 + 1];
  union { __bf16 h[8]; uint4 u; } p;
  p.h[0] = (__bf16)a.x; p.h[1] = (__bf16)a.y; p.h[2] = (__bf16)a.z; p.h[3] = (__bf16)a.w;
  p.h[4] = (__bf16)b.x; p.h[5] = (__bf16)b.y; p.h[6] = (__bf16)b.z; p.h[7] = (__bf16)b.w;
  reinterpret_cast<uint4*>(yp)[idx] = p.u;
}

// ---- bucketed CSR build --------------------------------------------------

__global__ __launch_bounds__(256) void k_bhist(const int* __restrict__ dst,
                                               int* __restrict__ bcnt, int E, int NB) {
  __shared__ int h[NBMAX];
  for (int i = threadIdx.x; i < NB; i += 256) h[i] = 0;
  __syncthreads();
  for (int e = blockIdx.x * 256 + threadIdx.x; e < E; e += gridDim.x * 256)
    atomicAdd(&h[dst[e] >> BSH], 1);
  __syncthreads();
  for (int i = threadIdx.x; i < NB; i += 256) {
    int c = h[i];
    if (c) atomicAdd(&bcnt[i], c);
  }
}

__global__ __launch_bounds__(1024) void k_bscan(const int* __restrict__ bcnt,
                                                int* __restrict__ bbase,
                                                int* __restrict__ bcur, int NB, int E) {
  __shared__ int sm[NBMAX];
  const int tid = threadIdx.x;
  int v = (tid < NB) ? bcnt[tid] : 0;
  sm[tid] = v;
  __syncthreads();
  for (int off = 1; off < NBMAX; off <<= 1) {
    int t = (tid >= off) ? sm[tid - off] : 0;
    __syncthreads();
    sm[tid] += t;
    __syncthreads();
  }
  if (tid < NB) {
    bbase[tid] = sm[tid] - v;
    bcur[tid] = sm[tid] - v;
  }
  if (tid == 0) bbase[NB] = E;
}

__global__ __launch_bounds__(256) void k_bscatter(const int* __restrict__ src,
                                                  const int* __restrict__ dst,
                                                  int* __restrict__ bcur,
                                                  int* __restrict__ ebuck, int E, int NB) {
  __shared__ int h[NBMAX];
  __shared__ int base[NBMAX];
  const int beg = blockIdx.x * CCHUNK;
  const int end = min(beg + CCHUNK, E);
  for (int i = threadIdx.x; i < NB; i += 256) h[i] = 0;
  __syncthreads();
  for (int e = beg + threadIdx.x; e < end; e += 256)
    atomicAdd(&h[dst[e] >> BSH], 1);
  __syncthreads();
  for (int i = threadIdx.x; i < NB; i += 256) {
    int c = h[i];
    base[i] = c ? atomicAdd(&bcur[i], c) : 0;
    h[i] = 0;  // becomes local rank cursor
  }
  __syncthreads();
  for (int e = beg + threadIdx.x; e < end; e += 256) {
    const int d = dst[e];
    const int b = d >> BSH;
    const int r = atomicAdd(&h[b], 1);
    ebuck[base[b] + r] = (src[e] << BSH) | (d & 127);
  }
}

__global__ __launch_bounds__(256) void k_bbuild(const int* __restrict__ ebuck,
                                                const int* __restrict__ bbase,
                                                int* __restrict__ row_ptr,
                                                int* __restrict__ esrc,
                                                float* __restrict__ inv, int N, int E) {
  __shared__ int cnt[128], s[128], cur[128];
  const int b = blockIdx.x;
  const int n0 = b << BSH;
  const int nn = min(128, N - n0);
  const int beg = bbase[b], end = bbase[b + 1];
  const int tid = threadIdx.x;
  if (tid < 128) cnt[tid] = 0;
  __syncthreads();
  for (int e = beg + tid; e < end; e += 256)
    atomicAdd(&cnt[ebuck[e] & 127], 1);
  __syncthreads();
  if (tid < 128) s[tid] = cnt[tid];
  __syncthreads();
  for (int off = 1; off < 128; off <<= 1) {
    int t = (tid < 128 && tid >= off) ? s[tid - off] : 0;
    __syncthreads();
    if (tid < 128) s[tid] += t;
    __syncthreads();
  }
  if (tid < 128) {
    const int ex = s[tid] - cnt[tid];
    cur[tid] = ex;
    if (tid < nn) {
      row_ptr[n0 + tid] = beg + ex;
      inv[n0 + tid] = 1.0f / fmaxf((float)cnt[tid], 1.0f);
    }
  }
  if (b == 0 && tid == 0) row_ptr[N] = E;
  __syncthreads();
  for (int e = beg + tid; e < end; e += 256) {
    const int p = ebuck[e];
    const int r = atomicAdd(&cur[p & 127], 1);
    esrc[beg + r] = p >> BSH;
  }
}

// ---- mean aggregation, quad-gather + packed f32 accumulate ---------------
// Quad q (16 lanes) handles 4 consecutive edges; lane loads uint4 = 8 bf16
// feats per row. One int4 load supplies the quad's 4 src indices. Accumulate
// into float2 (v_pk_add_f32: 2 feature-adds/instr). Cross-quad reduce via
// 2 shfl_xor rounds; quad 0 writes the row.

__device__ __forceinline__ void accp(f32x2& a, unsigned int u) {
  f32x2 v;
  v.x = __uint_as_float(u << 16);
  v.y = __uint_as_float(u & 0xffff0000u);
  a += v;
}

__device__ __forceinline__ void acc8p(f32x2 acc[4], const uint4& u) {
  accp(acc[0], u.x);
  accp(acc[1], u.y);
  accp(acc[2], u.z);
  accp(acc[3], u.w);
}

__global__ __launch_bounds__(256) void k_gather_mean(const ushort* __restrict__ h,
                                                     const int* __restrict__ row_ptr,
                                                     const int* __restrict__ esrc,
                                                     const float* __restrict__ inv,
                                                     ushort* __restrict__ out, int N) {
  const int node = blockIdx.x * 4 + (threadIdx.x >> 6);
  if (node >= N) return;
  const int lane = threadIdx.x & 63;
  const int q = lane >> 4;   // quad
  const int w = lane & 15;   // feature group [w*8, w*8+8)
  const int beg = row_ptr[node];
  const int end = row_ptr[node + 1];
  const ushort* hp = h + w * 8;
  f32x2 acc[4] = {{0.f, 0.f}, {0.f, 0.f}, {0.f, 0.f}, {0.f, 0.f}};
  int e = beg;
  for (; e + 15 < end; e += 16) {
    const int4 ss = *reinterpret_cast<const int4*>(esrc + e + q * 4);
    const uint4 u0 = *reinterpret_cast<const uint4*>(hp + (size_t)ss.x * D);
    const uint4 u1 = *reinterpret_cast<const uint4*>(hp + (size_t)ss.y * D);
    const uint4 u2 = *reinterpret_cast<const uint4*>(hp + (size_t)ss.z * D);
    const uint4 u3 = *reinterpret_cast<const uint4*>(hp + (size_t)ss.w * D);
    acc8p(acc, u0);
    acc8p(acc, u1);
    acc8p(acc, u2);
    acc8p(acc, u3);
  }
  for (; e + 3 < end; e += 4) {
    const int s0 = esrc[e + q];
    const uint4 u0 = *reinterpret_cast<const uint4*>(hp + (size_t)s0 * D);
    acc8p(acc, u0);
  }
  if (e + q < end) {
    const int s0 = esrc[e + q];
    const uint4 u0 = *reinterpret_cast<const uint4*>(hp + (size_t)s0 * D);
    acc8p(acc, u0);
  }
  // reduce across quads (all lanes participate)
#pragma unroll
  for (int i = 0; i < 4; ++i) {
    acc[i].x += __shfl_xor(acc[i].x, 16);
    acc[i].y += __shfl_xor(acc[i].y, 16);
    acc[i].x += __shfl_xor(acc[i].x, 32);
    acc[i].y += __shfl_xor(acc[i].y, 32);
  }
  if (q == 0) {
    const float iv = inv[node];
    union { __bf16 b[8]; uint4 u; } p;
#pragma unroll
    for (int i = 0; i < 4; ++i) {
      p.b[i * 2 + 0] = (__bf16)(acc[i].x * iv);
      p.b[i * 2 + 1] = (__bf16)(acc[i].y * iv);
    }
    *reinterpret_cast<uint4*>(out + (size_t)node * D + w * 8) = p.u;
  }
}

// ---- MFMA GEMM (layer 1): h1 = relu(A @ W^T + bias), 2 tiles/iter --------

__device__ __forceinline__ void gemm_tile16(const ushort* __restrict__ A,
                                            const B8 bfrag[2][4], const float bv[2],
                                            ushort* __restrict__ Hout, int mt,
                                            int l15, int quad, int wave) {
  const ushort* ap = A + (size_t)(mt * 16 + l15) * D + quad * 8;
  B8 a0, a1, a2, a3;
  a0.u = *reinterpret_cast<const uint4*>(ap);
  a1.u = *reinterpret_cast<const uint4*>(ap + 32);
  a2.u = *reinterpret_cast<const uint4*>(ap + 64);
  a3.u = *reinterpret_cast<const uint4*>(ap + 96);
#pragma unroll
  for (int t = 0; t < 2; ++t) {
    f32x4 acc = {0.f, 0.f, 0.f, 0.f};
    acc = __builtin_amdgcn_mfma_f32_16x16x32_bf16(a0.v, bfrag[t][0].v, acc, 0, 0, 0);
    acc = __builtin_amdgcn_mfma_f32_16x16x32_bf16(a1.v, bfrag[t][1].v, acc, 0, 0, 0);
    acc = __builtin_amdgcn_mfma_f32_16x16x32_bf16(a2.v, bfrag[t][2].v, acc, 0, 0, 0);
    acc = __builtin_amdgcn_mfma_f32_16x16x32_bf16(a3.v, bfrag[t][3].v, acc, 0, 0, 0);
    const int col = wave * 32 + t * 16 + l15;
#pragma unroll
    for (int r = 0; r < 4; ++r) {
      const int row = mt * 16 + quad * 4 + r;
      const float v = fmaxf(acc[r] + bv[t], 0.f);
      union { __bf16 b; ushort s; } c;
      c.b = (__bf16)v;
      Hout[(size_t)row * D + col] = c.s;
    }
  }
}

__global__ __launch_bounds__(256) void k_gemm_mfma(const ushort* __restrict__ A,
                                                   const ushort* __restrict__ Wb,
                                                   const float* __restrict__ bias,
                                                   ushort* __restrict__ Hout, int N) {
  const int wave = threadIdx.x >> 6;
  const int lane = threadIdx.x & 63;
  const int l15 = lane & 15;
  const int quad = lane >> 4;

  B8 bfrag[2][4];
  float bv[2];
#pragma unroll
  for (int t = 0; t < 2; ++t) {
    const int n = wave * 32 + t * 16 + l15;
    bv[t] = bias[n];
#pragma unroll
    for (int ks = 0; ks < 4; ++ks)
      bfrag[t][ks].u = *reinterpret_cast<const uint4*>(Wb + n * D + ks * 32 + quad * 8);
  }

  const int mtiles = N >> 4;
  const int pairs = mtiles >> 1;
  for (int p = blockIdx.x; p < pairs; p += gridDim.x) {
    gemm_tile16(A, bfrag, bv, Hout, p * 2 + 0, l15, quad, wave);
    gemm_tile16(A, bfrag, bv, Hout, p * 2 + 1, l15, quad, wave);
  }
  if ((mtiles & 1) && blockIdx.x == 0)
    gemm_tile16(A, bfrag, bv, Hout, mtiles - 1, l15, quad, wave);
}

// ---- fused layer-2 GEMM + logits + log_softmax ---------------------------

__global__ __launch_bounds__(256) void k_gemm2_logits(const ushort* __restrict__ A2,
                                                      const ushort* __restrict__ H1,
                                                      const ushort* __restrict__ W2b,
                                                      const float* __restrict__ b2,
                                                      const ushort* __restrict__ Wlb,
                                                      const float* __restrict__ bl,
                                                      float* __restrict__ out, int N) {
  __shared__ ushort H2t[16][136];
  __shared__ float L[16][NCLS + 4];
  const int wave = threadIdx.x >> 6;
  const int lane = threadIdx.x & 63;
  const int l15 = lane & 15;
  const int quad = lane >> 4;

  B8 bfrag2[2][4];
  float bv2[2];
#pragma unroll
  for (int t = 0; t < 2; ++t) {
    const int n = wave * 32 + t * 16 + l15;
    bv2[t] = b2[n];
#pragma unroll
    for (int ks = 0; ks < 4; ++ks)
      bfrag2[t][ks].u = *reinterpret_cast<const uint4*>(W2b + n * D + ks * 32 + quad * 8);
  }
  B8 bfragL[8];
  const int nl = wave * 16 + l15;
  const float bbl = bl[nl];
#pragma unroll
  for (int ks = 0; ks < 8; ++ks)
    bfragL[ks].u = *reinterpret_cast<const uint4*>(Wlb + nl * (2 * D) + ks * 32 + quad * 8);

  const int mtiles = N >> 4;
  for (int mt = blockIdx.x; mt < mtiles; mt += gridDim.x) {
    // ---- phase 1: h2 tile ----
    const ushort* ap = A2 + (size_t)(mt * 16 + l15) * D + quad * 8;
    B8 a0, a1, a2, a3;
    a0.u = *reinterpret_cast<const uint4*>(ap);
    a1.u = *reinterpret_cast<const uint4*>(ap + 32);
    a2.u = *reinterpret_cast<const uint4*>(ap + 64);
    a3.u = *reinterpret_cast<const uint4*>(ap + 96);
#pragma unroll
    for (int t = 0; t < 2; ++t) {
      f32x4 acc = {0.f, 0.f, 0.f, 0.f};
      acc = __builtin_amdgcn_mfma_f32_16x16x32_bf16(a0.v, bfrag2[t][0].v, acc, 0, 0, 0);
      acc = __builtin_amdgcn_mfma_f32_16x16x32_bf16(a1.v, bfrag2[t][1].v, acc, 0, 0, 0);
      acc = __builtin_amdgcn_mfma_f32_16x16x32_bf16(a2.v, bfrag2[t][2].v, acc, 0, 0, 0);
      acc = __builtin_amdgcn_mfma_f32_16x16x32_bf16(a3.v, bfrag2[t][3].v, acc, 0, 0, 0);
      const int col = wave * 32 + t * 16 + l15;
#pragma unroll
      for (int r = 0; r < 4; ++r) {
        const float v = fmaxf(acc[r] + bv2[t], 0.f);
        union { __bf16 b; ushort s; } c;
        c.b = (__bf16)v;
        H2t[quad * 4 + r][col] = c.s;
      }
    }
    __syncthreads();
    // ---- phase 2: logits ----
    const size_t rb = (size_t)(mt * 16 + l15) * D + quad * 8;
    f32x4 acc = {0.f, 0.f, 0.f, 0.f};
    B8 a;
#pragma unroll
    for (int ks = 0; ks < 4; ++ks) {
      a.u = *reinterpret_cast<const uint4*>(H1 + rb + ks * 32);
      acc = __builtin_amdgcn_mfma_f32_16x16x32_bf16(a.v, bfragL[ks].v, acc, 0, 0, 0);
    }
#pragma unroll
    for (int ks = 0; ks < 4; ++ks) {
      a.u = *reinterpret_cast<const uint4*>(&H2t[l15][ks * 32 + quad * 8]);
      acc = __builtin_amdgcn_mfma_f32_16x16x32_bf16(a.v, bfragL[4 + ks].v, acc, 0, 0, 0);
    }
#pragma unroll
    for (int r = 0; r < 4; ++r)
      L[quad * 4 + r][wave * 16 + l15] = acc[r] + bbl;
    __syncthreads();
    // ---- softmax ----
#pragma unroll
    for (int r = 0; r < 4; ++r) {
      const int row = wave * 4 + r;
      float v = L[row][lane];
      float m = v;
#pragma unroll
      for (int off = 32; off > 0; off >>= 1) m = fmaxf(m, __shfl_xor(m, off));
      float e = __expf(v - m);
#pragma unroll
      for (int off = 32; off > 0; off >>= 1) e += __shfl_xor(e, off);
      out[(size_t)(mt * 16 + row) * NCLS + lane] = v - m - __logf(e);
    }
    __syncthreads();
  }
}

// ---- driver --------------------------------------------------------------

extern "C" void kernel_launch(void* const* d_in, const int* in_sizes, int n_in,
                              void* d_out, int out_size, void* d_ws, size_t ws_size,
                              hipStream_t stream) {
  const float* feat = (const float*)d_in[0];
  const int* src = (const int*)d_in[1];
  const int* dst = (const int*)d_in[2];
  const float* W1 = (const float*)d_in[3];
  const float* b1 = (const float*)d_in[4];
  const float* W2 = (const float*)d_in[5];
  const float* b2 = (const float*)d_in[6];
  const float* Wl = (const float*)d_in[7];
  const float* bl = (const float*)d_in[8];
  float* out = (float*)d_out;

  const int N = in_sizes[0] / D;  // 100000
  const int E = in_sizes[1];      // 1600000
  const int NB = (N + 127) >> BSH;  // 782

  // workspace layout
  float* ws = (float*)d_ws;
  float* inv = ws;                          // N
  ushort* featb = (ushort*)(inv + N);       // N*D
  ushort* scratch = featb + (size_t)N * D;  // N*D (ebuck aliases, then agg)
  ushort* h1b = scratch + (size_t)N * D;    // N*D
  int* row_ptr = (int*)(h1b + (size_t)N * D);  // N+1
  int* esrc = row_ptr + N + 1;              // E
  int* bcnt = esrc + E;                     // NBMAX
  int* bbase = bcnt + NBMAX;                // NBMAX+1
  int* bcur = bbase + NBMAX + 1;            // NBMAX
  ushort* W1b = (ushort*)(bcur + NBMAX);    // D*D
  ushort* W2b = W1b + D * D;                // D*D
  ushort* Wlb = W2b + D * D;                // 2*D*NCLS
  int* ebuck = (int*)scratch;               // E ints, dead after k_bbuild

  // bf16 copies + bcnt zero (one launch)
  const int n8 = N * D / 8;
  const int prepTot = n8 + 2 * (D * D / 8) + (2 * D * NCLS / 8);
  k_prep<<<(prepTot + 255) / 256, 256, 0, stream>>>(feat, W1, W2, Wl,
                                                    featb, W1b, W2b, Wlb, bcnt, n8);

  // bucketed CSR build
  k_bhist<<<256, 256, 0, stream>>>(dst, bcnt, E, NB);
  k_bscan<<<1, 1024, 0, stream>>>(bcnt, bbase, bcur, NB, E);
  k_bscatter<<<(E + CCHUNK - 1) / CCHUNK, 256, 0, stream>>>(src, dst, bcur, ebuck, E, NB);
  k_bbuild<<<NB, 256, 0, stream>>>(ebuck, bbase, row_ptr, esrc, inv, N, E);

  const int gatherBlocks = (N + 3) / 4;
  ushort* aggb = scratch;

  // layer 1
  k_gather_mean<<<gatherBlocks, 256, 0, stream>>>(featb, row_ptr, esrc, inv, aggb, N);
  k_gemm_mfma<<<2048, 256, 0, stream>>>(aggb, W1b, b1, h1b, N);

  // layer 2 gather + fused GEMM/logits/softmax
  k_gather_mean<<<gatherBlocks, 256, 0, stream>>>(h1b, row_ptr, esrc, inv, aggb, N);
  k_gemm2_logits<<<2048, 256, 0, stream>>>(aggb, h1b, W2b, b2, Wlb, bl, out, N);
}